// Round 10
// baseline (180.653 us; speedup 1.0000x reference)
//
#include <hip/hip_runtime.h>

#define S_LEN 2048
#define NH 32
#define NKV 8
#define HD 128
#define WINDOW 1024
#define NEG_INF_F -1e30f
// -log2(10000)/64
#define NEG_L2_10K_O64 -0.2076205059304601f
#define LOG2E_F 1.442695040888963f

typedef unsigned short ushort_t;
typedef __attribute__((ext_vector_type(4))) short bf16x4;
typedef __attribute__((ext_vector_type(8))) short short8;
typedef __attribute__((ext_vector_type(2))) unsigned uint2v;
typedef __attribute__((ext_vector_type(4))) float floatx4;

static __device__ __forceinline__ float fexp2(float x) {
  return __builtin_amdgcn_exp2f(x);
}

static __device__ __forceinline__ ushort_t f2bf(float f) {
  union { float f; unsigned u; } un; un.f = f;
  unsigned r = un.u + 0x7fffu + ((un.u >> 16) & 1u);
  return (ushort_t)(r >> 16);
}

static __device__ __forceinline__ unsigned pack2bf(float a, float b) {
  return (unsigned)f2bf(a) | ((unsigned)f2bf(b) << 16);
}

// half-up-round packed bf16 (P only; P>=0): 2 v_add + 1 v_perm
static __device__ __forceinline__ unsigned packP(float a, float b) {
  unsigned ua = __builtin_bit_cast(unsigned, a) + 0x8000u;
  unsigned ub = __builtin_bit_cast(unsigned, b) + 0x8000u;
  return __builtin_amdgcn_perm(ub, ua, 0x07060302u);  // [b_hi16 : a_hi16]
}

// ---------------- pre-pass: RoPE K and transpose V into FRAGMENT-LINEAR layouts.
// Kr: [kv][chunk(64)][kh(2)][t(4)][lane(64)][e(8)]  (2048 ushorts per chunk-half)
//   slot (t,lane=quad*16+l16) holds K[kh*16+l16][d = (4t+quad)*8 + e]
//   -> attn's kf[t] load = 64 lanes x 16B CONTIGUOUS (1KB wave-load).
// Vt: [kv][chunk(64)][kh(2)][dt(8)][lane(64)][jj(4)]  (2048 ushorts per chunk-half)
//   slot (dt,lane=quad*16+l16,jj) holds V[key = kh*16+quad*4+jj][d = dt*16+l16]
//   -> attn's vf[dt] load = 64 lanes x 8B CONTIGUOUS (512B wave-load).
__global__ __launch_bounds__(256) void prep_kv(
    const float* __restrict__ k, const float* __restrict__ v,
    const int* __restrict__ positions, ushort_t* __restrict__ Kr,
    ushort_t* __restrict__ Vt) {
  __shared__ float lv[64][129];
  const int kv = blockIdx.x & 7;
  const int s0 = (blockIdx.x >> 3) * 64;
  const int tid = threadIdx.x;
  {
    const int i = tid & 63;
    const int wrow = tid >> 6;
    const float invf = fexp2((float)i * NEG_L2_10K_O64);
    // K store offset pieces for d=i (o1); d=i+64 (o2) lands at +1024 (t += 2)
    const int kframe = (i >> 5) * 512 + (((i >> 3) & 3) * 16) * 8 + (i & 7);
#pragma unroll 4
    for (int it = 0; it < 16; ++it) {
      int s = s0 + it * 4 + wrow;
      float pos = (float)positions[s];
      const float* kp = k + ((size_t)s * NKV + kv) * HD;
      float x1 = kp[i], x2 = kp[i + 64];
      float sn, cs;
      __sincosf(pos * invf, &sn, &cs);
      const int ch = (s >> 5) * 2 + ((s >> 4) & 1);
      ushort_t* ko = Kr + (size_t)kv * 262144 + ch * 2048 + kframe + (s & 15) * 8;
      ko[0] = f2bf(x1 * cs - x2 * sn);
      ko[1024] = f2bf(x2 * cs + x1 * sn);
    }
  }
  {
    const int d = tid & 127;
    const int r2 = tid >> 7;
#pragma unroll
    for (int it = 0; it < 32; ++it) {
      int row = it * 2 + r2;
      lv[row][d] = v[((size_t)(s0 + row) * NKV + kv) * HD + d];
    }
  }
  __syncthreads();
  {
    // write V pairs (keys 2j,2j+1 share a u32) into fragment-linear layout
    unsigned* Vreg = (unsigned*)Vt + (size_t)kv * 131072 + (s0 >> 6) * 4096;
#pragma unroll
    for (int it = 0; it < 16; ++it) {
      int idx = it * 256 + tid;
      int d = idx >> 5, j = idx & 31;
      int o = (j >> 3) * 1024 + (d >> 4) * 128 +
              (((j >> 1) & 3) * 16 + (d & 15)) * 2 + (j & 1);
      Vreg[o] = pack2bf(lv[2 * j][d], lv[2 * j + 1][d]);
    }
  }
}

// ---------------- main flash attention kernel
// block = 4 waves; wave (hp,kh) = heads {kv*4+2hp, +1} x key-half kh of each 32-key chunk.
// grid = 768: per kv, 64 full-window tiles + 32 ramp-pair blocks -> every block ~33 chunks,
// exactly 3 blocks/CU resident.
// NO LDS IN THE MAIN LOOP: K/V fragments are read directly from the fragment-linear
// global layouts (perfectly coalesced 1KB / 512B wave-loads, L1/L2-served, kv->XCD
// affine). ZERO barriers between Q-load and epilogue; waves fully independent.
// K frags register-prefetched 1 chunk ahead; V issued at iteration top (~160cy slack).
// PV via v_mfma_f32_16x16x16_bf16 whose B-frag layout equals QK's S-output layout
// (P never crosses lanes).
__global__ __launch_bounds__(256, 3) void attn_kernel(
    const float* __restrict__ q, const int* __restrict__ positions,
    const float* __restrict__ sinks, const ushort_t* __restrict__ Kr,
    const ushort_t* __restrict__ Vt, float* __restrict__ out) {
  // 16 KB: Q staging (4 x 2048 ushorts) pre-loop; epilogue planes (4096 floats).
  __shared__ __align__(16) ushort_t smem[8192];
  __shared__ float lsx[64];

  const int tid = threadIdx.x;
  const int w = tid >> 6;
  const int lane = tid & 63;
  const int quad = lane >> 4;
  const int l16 = lane & 15;
  const int hp = w >> 1;
  const int kh = w & 1;
  const int kv = blockIdx.x & 7;   // XCD-affine: each kv's K/V slice stays in one L2
  const int bid = blockIdx.x >> 3;
  const int h0 = kv * 4 + hp * 2;
  const float QSCALE = (float)(0.08838834764831845 * 1.4426950408889634);

  const ushort_t* KrH = Kr + (size_t)kv * 262144;
  const ushort_t* VtH = Vt + (size_t)kv * 262144;

  int tiles[2];
  int ntiles;
  if (bid < 64) { tiles[0] = bid + 64; tiles[1] = 0; ntiles = 1; }
  else          { tiles[0] = bid - 64; tiles[1] = 127 - bid; ntiles = 2; }

  // chunk-invariant fragment offsets (ushort units) within a chunk-half region
  const int klo = lane * 8;   // + t*512
  const int vlo = lane * 4;   // + dt*256

  for (int ti = 0; ti < ntiles; ++ti) {
    const int tile = tiles[ti];
    const int q0 = tile * 16;

    // ---- Q RoPE (+SCALE*log2e fold): wave w stages head kv*4+w into region w
    {
      const int hw = kv * 4 + w;
      ushort_t* Qsw = smem + w * 2048;
      const float invf = fexp2((float)lane * NEG_L2_10K_O64);
#pragma unroll 4
      for (int row = 0; row < 16; ++row) {
        float pos = (float)positions[q0 + row];
        const float* qp = q + ((size_t)(q0 + row) * NH + hw) * HD;
        float x1 = qp[lane], x2 = qp[lane + 64];
        float sn, cs;
        __sincosf(pos * invf, &sn, &cs);
        float o1 = (x1 * cs - x2 * sn) * QSCALE;
        float o2 = (x2 * cs + x1 * sn) * QSCALE;
        int c1_ = (lane >> 3) ^ row;
        int c2_ = ((lane >> 3) + 8) ^ row;
        Qsw[row * 128 + c1_ * 8 + (lane & 7)] = f2bf(o1);
        Qsw[row * 128 + c2_ * 8 + (lane & 7)] = f2bf(o2);
      }
    }
    __syncthreads();
    short8 qf0[4], qf1[4];   // B-operands for heads 2hp, 2hp+1
    {
      const ushort_t* Qr0 = smem + (hp * 2) * 2048;
      const ushort_t* Qr1 = smem + (hp * 2 + 1) * 2048;
#pragma unroll
      for (int t = 0; t < 4; ++t) {
        int off = l16 * 128 + (((4 * t + quad) ^ l16) * 8);
        qf0[t] = *(const short8*)&Qr0[off];
        qf1[t] = *(const short8*)&Qr1[off];
      }
    }

    floatx4 OA[8], OB[8];
#pragma unroll
    for (int i = 0; i < 8; ++i) {
      OA[i] = (floatx4){0.f, 0.f, 0.f, 0.f};
      OB[i] = (floatx4){0.f, 0.f, 0.f, 0.f};
    }
    float lsumA = 0.f, lsumB = 0.f;

    const int cbeg = (q0 > 1023) ? ((q0 - 1023) >> 5) : 0;
    const int cend = (q0 + 15) >> 5;

    // ---- prologue: K frags of chunk cbeg into registers
    short8 kcur[4];
    {
      const ushort_t* kp = KrH + (size_t)(cbeg * 2 + kh) * 2048 + klo;
#pragma unroll
      for (int t = 0; t < 4; ++t) kcur[t] = *(const short8*)(kp + t * 512);
    }

    for (int ci = cbeg; ci <= cend; ++ci) {
      const int koff = ci * 32;
      // prefetch next chunk's K frags (coalesced 1KB wave-loads)
      short8 knxt[4];
      const bool more = (ci < cend);
      if (more) {
        const ushort_t* kn = KrH + (size_t)((ci + 1) * 2 + kh) * 2048 + klo;
#pragma unroll
        for (int t = 0; t < 4; ++t) knxt[t] = *(const short8*)(kn + t * 512);
      }
      // V frags of current chunk (coalesced 512B wave-loads; used after QK+softmax)
      bf16x4 vf[8];
      {
        const ushort_t* vp = VtH + (size_t)(ci * 2 + kh) * 2048 + vlo;
#pragma unroll
        for (int dt = 0; dt < 8; ++dt) vf[dt] = *(const bf16x4*)(vp + dt * 256);
      }

      // S^T = K_half . Q^T for both heads (rows=16 keys of this kh, cols=16 q)
      floatx4 sA = {0.f, 0.f, 0.f, 0.f}, sB = {0.f, 0.f, 0.f, 0.f};
#pragma unroll
      for (int t = 0; t < 4; ++t) {
        sA = __builtin_amdgcn_mfma_f32_16x16x32_bf16(kcur[t], qf0[t], sA, 0, 0, 0);
        sB = __builtin_amdgcn_mfma_f32_16x16x32_bf16(kcur[t], qf1[t], sB, 0, 0, 0);
      }

      if (koff + 31 > q0 || koff < q0 - 1008) {   // edge chunks only
        const int qp_ = q0 + l16;
        const int kb_ = koff + kh * 16 + quad * 4;
#pragma unroll
        for (int r = 0; r < 4; ++r) {
          int ki = kb_ + r;
          bool ok = (ki <= qp_) && (qp_ - ki < WINDOW);
          if (!ok) { sA[r] = NEG_INF_F; sB[r] = NEG_INF_F; }
        }
      }

      // p = 2^score (scores already in log2 units; bounded ~10 so no shift needed)
      float pA[4], pB[4];
#pragma unroll
      for (int r = 0; r < 4; ++r) { pA[r] = fexp2(sA[r]); pB[r] = fexp2(sB[r]); }
      lsumA += (pA[0] + pA[1]) + (pA[2] + pA[3]);
      lsumB += (pB[0] + pB[1]) + (pB[2] + pB[3]);

      // P is ALREADY in 16x16x16 B-frag layout: lane holds B[k=quad*4+j][n=l16].
      uint2v ua, ub;
      ua[0] = packP(pA[0], pA[1]); ua[1] = packP(pA[2], pA[3]);
      ub[0] = packP(pB[0], pB[1]); ub[1] = packP(pB[2], pB[3]);
      bf16x4 pfA = __builtin_bit_cast(bf16x4, ua);
      bf16x4 pfB = __builtin_bit_cast(bf16x4, ub);

      // O^T += V^T . P^T via 16x16x16: A-frag = V^T[dt*16+l16][4 keys of this quad]
#pragma unroll
      for (int dt = 0; dt < 8; ++dt) {
        OA[dt] = __builtin_amdgcn_mfma_f32_16x16x16bf16_1k(vf[dt], pfA, OA[dt], 0, 0, 0);
        OB[dt] = __builtin_amdgcn_mfma_f32_16x16x16bf16_1k(vf[dt], pfB, OB[dt], 0, 0, 0);
      }

      if (more) {
#pragma unroll
        for (int t = 0; t < 4; ++t) kcur[t] = knxt[t];
      }
      // no barrier: waves fully independent in this loop
    }
    __syncthreads();   // rendezvous before epilogue LDS use

    // ---- epilogue: combine kh partials via LDS, normalize, store
    lsumA += __shfl_xor(lsumA, 16); lsumA += __shfl_xor(lsumA, 32);
    lsumB += __shfl_xor(lsumB, 16); lsumB += __shfl_xor(lsumB, 32);
    float* Lf = (float*)smem;
    const int lfb = lane * 4;   // plane-major: contiguous 1KB per wave access
    float rlA = 0.f, rlB = 0.f;

    if (kh == 1 && quad == 0) {
      lsx[hp * 32 + l16] = lsumA;
      lsx[hp * 32 + 16 + l16] = lsumB;
    }
    // two rounds (16KB of planes each): m=0 -> dt 0..3, m=1 -> dt 4..7
#pragma unroll
    for (int m = 0; m < 2; ++m) {
      if (kh == 1) {
#pragma unroll
        for (int t = 0; t < 4; ++t) {
          *(floatx4*)&Lf[((hp * 2 + 0) * 4 + t) * 256 + lfb] = OA[m * 4 + t];
          *(floatx4*)&Lf[((hp * 2 + 1) * 4 + t) * 256 + lfb] = OB[m * 4 + t];
        }
      }
      __syncthreads();
      if (kh == 0) {
        if (m == 0) {
          float denA = lsumA + lsx[hp * 32 + l16] + fexp2(sinks[h0] * LOG2E_F);
          float denB = lsumB + lsx[hp * 32 + 16 + l16] + fexp2(sinks[h0 + 1] * LOG2E_F);
          rlA = 1.0f / denA;
          rlB = 1.0f / denB;
        }
        float* opA = out + ((size_t)(q0 + l16) * NH + h0) * HD + quad * 4;
        float* opB = opA + HD;
#pragma unroll
        for (int t = 0; t < 4; ++t) {
          floatx4 pv = *(const floatx4*)&Lf[((hp * 2 + 0) * 4 + t) * 256 + lfb];
          floatx4 vv;
#pragma unroll
          for (int e = 0; e < 4; ++e) vv[e] = (OA[m * 4 + t][e] + pv[e]) * rlA;
          *(floatx4*)(opA + (m * 4 + t) * 16) = vv;
          pv = *(const floatx4*)&Lf[((hp * 2 + 1) * 4 + t) * 256 + lfb];
#pragma unroll
          for (int e = 0; e < 4; ++e) vv[e] = (OB[m * 4 + t][e] + pv[e]) * rlB;
          *(floatx4*)(opB + (m * 4 + t) * 16) = vv;
        }
      }
      __syncthreads();   // also frees smem for next tile's Q staging
    }
  }
}

extern "C" void kernel_launch(void* const* d_in, const int* in_sizes, int n_in,
                              void* d_out, int out_size, void* d_ws, size_t ws_size,
                              hipStream_t stream) {
  const float* q = (const float*)d_in[0];
  const float* k = (const float*)d_in[1];
  const float* v = (const float*)d_in[2];
  const int* positions = (const int*)d_in[3];
  const float* sinks = (const float*)d_in[4];
  float* out = (float*)d_out;

  ushort_t* Kr = (ushort_t*)d_ws;                   // 4 MB (fragment-linear)
  ushort_t* Vt = Kr + (size_t)NKV * S_LEN * HD;     // 4 MB (fragment-linear)

  prep_kv<<<NKV * (S_LEN / 64), 256, 0, stream>>>(k, v, positions, Kr, Vt);
  attn_kernel<<<NKV * 96, 256, 0, stream>>>(q, positions, sinks, Kr, Vt, out);
}

// Round 11
// 132.847 us; speedup vs baseline: 1.3599x; 1.3599x over previous
//
#include <hip/hip_runtime.h>

#define S_LEN 2048
#define NH 32
#define NKV 8
#define HD 128
#define WINDOW 1024
#define NEG_INF_F -1e30f
// -log2(10000)/64
#define NEG_L2_10K_O64 -0.2076205059304601f
#define LOG2E_F 1.442695040888963f

typedef unsigned short ushort_t;
typedef __attribute__((ext_vector_type(4))) short bf16x4;
typedef __attribute__((ext_vector_type(8))) short short8;
typedef __attribute__((ext_vector_type(2))) unsigned uint2v;
typedef __attribute__((ext_vector_type(4))) float floatx4;

static __device__ __forceinline__ float fexp2(float x) {
  return __builtin_amdgcn_exp2f(x);
}

static __device__ __forceinline__ ushort_t f2bf(float f) {
  union { float f; unsigned u; } un; un.f = f;
  unsigned r = un.u + 0x7fffu + ((un.u >> 16) & 1u);
  return (ushort_t)(r >> 16);
}

static __device__ __forceinline__ unsigned pack2bf(float a, float b) {
  return (unsigned)f2bf(a) | ((unsigned)f2bf(b) << 16);
}

// half-up-round packed bf16 (P only; P>=0): 2 v_add + 1 v_perm
static __device__ __forceinline__ unsigned packP(float a, float b) {
  unsigned ua = __builtin_bit_cast(unsigned, a) + 0x8000u;
  unsigned ub = __builtin_bit_cast(unsigned, b) + 0x8000u;
  return __builtin_amdgcn_perm(ub, ua, 0x07060302u);  // [b_hi16 : a_hi16]
}

__device__ __forceinline__ void gl_lds16(const ushort_t* g, ushort_t* l) {
  __builtin_amdgcn_global_load_lds(
      (const __attribute__((address_space(1))) unsigned int*)g,
      (__attribute__((address_space(3))) unsigned int*)l, 16, 0, 0);
}

// ---------------- pre-pass: RoPE K -> Kr[kv][s][d]; V -> Vt tiled [kv][s/64][d][s%64]
// 16-row s-blocks: grid = NKV*128 = 1024 blocks = 4 blocks/CU (16 waves/CU) -- the
// old 64-row version ran 256 blocks = 1 wave/SIMD, pure latency exposure.
__global__ __launch_bounds__(256) void prep_kv(
    const float* __restrict__ k, const float* __restrict__ v,
    const int* __restrict__ positions, ushort_t* __restrict__ Kr,
    ushort_t* __restrict__ Vt) {
  __shared__ float lv[16][129];
  const int kv = blockIdx.x & 7;
  const int s0 = (blockIdx.x >> 3) * 16;
  const int tid = threadIdx.x;
  {
    const int i = tid & 63;
    const int wrow = tid >> 6;
    const float invf = fexp2((float)i * NEG_L2_10K_O64);
#pragma unroll
    for (int it = 0; it < 4; ++it) {
      int s = s0 + it * 4 + wrow;
      float pos = (float)positions[s];
      const float* kp = k + ((size_t)s * NKV + kv) * HD;
      float x1 = kp[i], x2 = kp[i + 64];
      float sn, cs;
      __sincosf(pos * invf, &sn, &cs);
      ushort_t* o = Kr + ((size_t)kv * S_LEN + s) * HD;
      o[i] = f2bf(x1 * cs - x2 * sn);
      o[i + 64] = f2bf(x2 * cs + x1 * sn);
    }
  }
  {
    const int d = tid & 127;
    const int r2 = tid >> 7;
#pragma unroll
    for (int it = 0; it < 8; ++it) {
      int row = it * 2 + r2;
      lv[row][d] = v[((size_t)(s0 + row) * NKV + kv) * HD + d];
    }
  }
  __syncthreads();
  {
    // this 16-row block fills s-pair columns jg0..jg0+7 of the (kv, s0>>6) 64-tile
    unsigned* Vreg = (unsigned*)(Vt + ((size_t)(kv * 32 + (s0 >> 6)) * HD) * 64);
    const int jg0 = (s0 & 63) >> 1;
#pragma unroll
    for (int it = 0; it < 4; ++it) {
      int idx = it * 256 + tid;          // 0..1023
      int d = idx >> 3, jl = idx & 7;
      Vreg[d * 32 + jg0 + jl] = pack2bf(lv[2 * jl][d], lv[2 * jl + 1][d]);
    }
  }
}

// ---------------- main flash attention kernel (unchanged from round 9 -- best measured)
// block = 4 waves; wave (hp,kh) = heads {kv*4+2hp, +1} x key-half kh of each 32-key chunk.
// grid = 768: per kv, 64 full-window tiles + 32 ramp-pair blocks -> every block ~33 chunks,
// exactly 3 blocks/CU resident.
// PV path: v_mfma_f32_16x16x16_bf16; its B-frag layout matches the QK S-output layout
// exactly -> P feeds PV with zero cross-lane ops. V LDS granule permutation
// place = d*4 + (kb8 ^ (d>>2)) keeps the b64 V-reads ~conflict-free.
// THREE K/V buffer pairs (staged 2 chunks ahead, plain __syncthreads per chunk): this
// makes buffer (b+1)%3 complete AND race-free during iter i, so the K fragments of
// chunk i+1 are prefetched into REGISTERS during chunk i -> iteration i+1's QK starts
// on register operands (no ds_read latency at the chain head).
__global__ __launch_bounds__(256, 3) void attn_kernel(
    const float* __restrict__ q, const int* __restrict__ positions,
    const float* __restrict__ sinks, const ushort_t* __restrict__ Kr,
    const ushort_t* __restrict__ Vt, float* __restrict__ out) {
  // 48 KB (ushort units): K bufs 3x4096 @ 0/4096/8192; V bufs 3x4096 @ 12288/16384/20480.
  // Q staging reuses 0..8191 (pre-loop); epilogue planes reuse 0..8191 (16KB floats).
  __shared__ __align__(16) ushort_t smem[24576];
  __shared__ float lsx[64];

  const int tid = threadIdx.x;
  const int w = tid >> 6;
  const int lane = tid & 63;
  const int quad = lane >> 4;
  const int l16 = lane & 15;
  const int hp = w >> 1;
  const int kh = w & 1;
  const int kv = blockIdx.x & 7;   // XCD-affine: each kv's K/V slice stays in one L2
  const int bid = blockIdx.x >> 3;
  const int h0 = kv * 4 + hp * 2;
  const float QSCALE = (float)(0.08838834764831845 * 1.4426950408889634);

  const ushort_t* KrH = Kr + (size_t)kv * S_LEN * HD;
  const ushort_t* VtH = Vt + (size_t)kv * 32 * HD * 64;

  int tiles[2];
  int ntiles;
  if (bid < 64) { tiles[0] = bid + 64; tiles[1] = 0; ntiles = 1; }
  else          { tiles[0] = bid - 64; tiles[1] = 127 - bid; ntiles = 2; }

  // staging maps (chunk-invariant)
  int kgo0, kgo1, vgo0, vgo1;
  { int key = tid >> 4;          kgo0 = key * HD + (((tid & 15) ^ (key & 15)) * 8); }
  { int s2 = 256 + tid; int key = s2 >> 4;
                                 kgo1 = key * HD + (((s2 & 15) ^ (key & 15)) * 8); }
  // V: dest granule n holds source tile (d = n>>2, kb8 = (n&3) ^ ((n>>4)&3))
  { int n = tid;       vgo0 = (n >> 2) * 64 + (((n & 3) ^ ((n >> 4) & 3)) * 8); }
  { int n = 256 + tid; vgo1 = (n >> 2) * 64 + (((n & 3) ^ ((n >> 4) & 3)) * 8); }
  const int kdst0 = (tid & 192) * 8;
  const int kdst1 = (256 + (tid & 192)) * 8;
  const int vdst0 = (tid & 192) * 8;
  const int vdst1 = 2048 + (tid & 192) * 8;
  // V read offset (ushorts): place = l16*4 + (kb8 ^ (l16>>2)), 8B granule half by quad&1
  const int kb8 = kh * 2 + (quad >> 1);
  const int vrd = (l16 * 4 + (kb8 ^ (l16 >> 2))) * 8 + (quad & 1) * 4;
  // K fragment read offsets within a K buffer (chunk-invariant)
  int kro[4];
#pragma unroll
  for (int t = 0; t < 4; ++t)
    kro[t] = (kh * 16) * 128 + l16 * 128 + (((4 * t + quad) ^ l16) * 8);

  auto stage = [&](int b, int koff) {
    const ushort_t* kb = KrH + (size_t)koff * HD;
    const ushort_t* vb = VtH + (size_t)(koff >> 6) * HD * 64 + (koff & 32);
    ushort_t* Kb = smem + b * 4096;
    ushort_t* Vb = smem + 12288 + b * 4096;
    gl_lds16(kb + kgo0, Kb + kdst0);
    gl_lds16(kb + kgo1, Kb + kdst1);
    gl_lds16(vb + vgo0, Vb + vdst0);
    gl_lds16(vb + vgo1, Vb + vdst1);
  };

  for (int ti = 0; ti < ntiles; ++ti) {
    const int tile = tiles[ti];
    const int q0 = tile * 16;

    // ---- Q RoPE (+SCALE*log2e fold): wave w stages head kv*4+w into region w
    {
      const int hw = kv * 4 + w;
      ushort_t* Qsw = smem + w * 2048;
      const float invf = fexp2((float)lane * NEG_L2_10K_O64);
#pragma unroll 4
      for (int row = 0; row < 16; ++row) {
        float pos = (float)positions[q0 + row];
        const float* qp = q + ((size_t)(q0 + row) * NH + hw) * HD;
        float x1 = qp[lane], x2 = qp[lane + 64];
        float sn, cs;
        __sincosf(pos * invf, &sn, &cs);
        float o1 = (x1 * cs - x2 * sn) * QSCALE;
        float o2 = (x2 * cs + x1 * sn) * QSCALE;
        int c1_ = (lane >> 3) ^ row;
        int c2_ = ((lane >> 3) + 8) ^ row;
        Qsw[row * 128 + c1_ * 8 + (lane & 7)] = f2bf(o1);
        Qsw[row * 128 + c2_ * 8 + (lane & 7)] = f2bf(o2);
      }
    }
    __syncthreads();
    short8 qf0[4], qf1[4];   // B-operands for heads 2hp, 2hp+1
    {
      const ushort_t* Qr0 = smem + (hp * 2) * 2048;
      const ushort_t* Qr1 = smem + (hp * 2 + 1) * 2048;
#pragma unroll
      for (int t = 0; t < 4; ++t) {
        int off = l16 * 128 + (((4 * t + quad) ^ l16) * 8);
        qf0[t] = *(const short8*)&Qr0[off];
        qf1[t] = *(const short8*)&Qr1[off];
      }
    }
    __syncthreads();   // qf reads complete before staging overwrites this region

    floatx4 OA[8], OB[8];
#pragma unroll
    for (int i = 0; i < 8; ++i) {
      OA[i] = (floatx4){0.f, 0.f, 0.f, 0.f};
      OB[i] = (floatx4){0.f, 0.f, 0.f, 0.f};
    }
    float lsumA = 0.f, lsumB = 0.f;

    const int cbeg = (q0 > 1023) ? ((q0 - 1023) >> 5) : 0;
    const int cend = (q0 + 15) >> 5;

    // ---- prologue: stage chunks cbeg, cbeg+1 into buffers 0,1; drain both
    stage(0, cbeg * 32);
    if (cbeg < cend) stage(1, cbeg * 32 + 32);
    __syncthreads();

    // preload K frags of chunk cbeg into registers
    short8 kcur[4];
#pragma unroll
    for (int t = 0; t < 4; ++t) kcur[t] = *(const short8*)&smem[kro[t]];

    int b = 0;
    for (int ci = cbeg; ci <= cend; ++ci) {
      const int koff = ci * 32;
      // stage 2 chunks ahead into buffer (b+2)%3
      if (ci + 2 <= cend) {
        int bp2 = (b >= 1) ? (b - 1) : (b + 2);
        stage(bp2, koff + 64);
      }
      // prefetch NEXT chunk's K frags from buffer (b+1)%3 (complete + race-free)
      const int bn = (b == 2) ? 0 : b + 1;
      short8 knxt[4];
      {
        const ushort_t* KsN = smem + bn * 4096;
#pragma unroll
        for (int t = 0; t < 4; ++t) knxt[t] = *(const short8*)&KsN[kro[t]];
      }

      // S^T = K_half . Q^T for both heads (rows=16 keys of this kh, cols=16 q)
      floatx4 sA = {0.f, 0.f, 0.f, 0.f}, sB = {0.f, 0.f, 0.f, 0.f};
#pragma unroll
      for (int t = 0; t < 4; ++t) {
        sA = __builtin_amdgcn_mfma_f32_16x16x32_bf16(kcur[t], qf0[t], sA, 0, 0, 0);
        sB = __builtin_amdgcn_mfma_f32_16x16x32_bf16(kcur[t], qf1[t], sB, 0, 0, 0);
      }

      if (koff + 31 > q0 || koff < q0 - 1008) {   // edge chunks only
        const int qp_ = q0 + l16;
        const int kb_ = koff + kh * 16 + quad * 4;
#pragma unroll
        for (int r = 0; r < 4; ++r) {
          int ki = kb_ + r;
          bool ok = (ki <= qp_) && (qp_ - ki < WINDOW);
          if (!ok) { sA[r] = NEG_INF_F; sB[r] = NEG_INF_F; }
        }
      }

      // p = 2^score (scores already in log2 units; bounded ~10 so no shift needed)
      float pA[4], pB[4];
#pragma unroll
      for (int r = 0; r < 4; ++r) { pA[r] = fexp2(sA[r]); pB[r] = fexp2(sB[r]); }
      lsumA += (pA[0] + pA[1]) + (pA[2] + pA[3]);
      lsumB += (pB[0] + pB[1]) + (pB[2] + pB[3]);

      // P is ALREADY in 16x16x16 B-frag layout: lane holds B[k=quad*4+j][n=l16].
      uint2v ua, ub;
      ua[0] = packP(pA[0], pA[1]); ua[1] = packP(pA[2], pA[3]);
      ub[0] = packP(pB[0], pB[1]); ub[1] = packP(pB[2], pB[3]);
      bf16x4 pfA = __builtin_bit_cast(bf16x4, ua);
      bf16x4 pfB = __builtin_bit_cast(bf16x4, ub);

      // O^T += V^T . P^T via 16x16x16: A-frag = lane reads V^T[dt*16+l16][4 keys]
      const ushort_t* VsB = smem + 12288 + b * 4096;
#pragma unroll
      for (int dt = 0; dt < 8; ++dt) {
        bf16x4 vf = *(const bf16x4*)&VsB[vrd + dt * 512];
        OA[dt] = __builtin_amdgcn_mfma_f32_16x16x16bf16_1k(vf, pfA, OA[dt], 0, 0, 0);
        OB[dt] = __builtin_amdgcn_mfma_f32_16x16x16bf16_1k(vf, pfB, OB[dt], 0, 0, 0);
      }

      __syncthreads();   // releases buffer b for restaging; drains in-flight stage
#pragma unroll
      for (int t = 0; t < 4; ++t) kcur[t] = knxt[t];
      b = bn;
    }

    // ---- epilogue: combine kh partials via LDS, normalize, store
    lsumA += __shfl_xor(lsumA, 16); lsumA += __shfl_xor(lsumA, 32);
    lsumB += __shfl_xor(lsumB, 16); lsumB += __shfl_xor(lsumB, 32);
    float* Lf = (float*)smem;
    const int lfb = lane * 4;   // plane-major: contiguous 1KB per wave access
    float rlA = 0.f, rlB = 0.f;

    if (kh == 1 && quad == 0) {
      lsx[hp * 32 + l16] = lsumA;
      lsx[hp * 32 + 16 + l16] = lsumB;
    }
    // two rounds (16KB of planes each): m=0 -> dt 0..3, m=1 -> dt 4..7
#pragma unroll
    for (int m = 0; m < 2; ++m) {
      if (kh == 1) {
#pragma unroll
        for (int t = 0; t < 4; ++t) {
          *(floatx4*)&Lf[((hp * 2 + 0) * 4 + t) * 256 + lfb] = OA[m * 4 + t];
          *(floatx4*)&Lf[((hp * 2 + 1) * 4 + t) * 256 + lfb] = OB[m * 4 + t];
        }
      }
      __syncthreads();
      if (kh == 0) {
        if (m == 0) {
          float denA = lsumA + lsx[hp * 32 + l16] + fexp2(sinks[h0] * LOG2E_F);
          float denB = lsumB + lsx[hp * 32 + 16 + l16] + fexp2(sinks[h0 + 1] * LOG2E_F);
          rlA = 1.0f / denA;
          rlB = 1.0f / denB;
        }
        float* opA = out + ((size_t)(q0 + l16) * NH + h0) * HD + quad * 4;
        float* opB = opA + HD;
#pragma unroll
        for (int t = 0; t < 4; ++t) {
          floatx4 pv = *(const floatx4*)&Lf[((hp * 2 + 0) * 4 + t) * 256 + lfb];
          floatx4 vv;
#pragma unroll
          for (int e = 0; e < 4; ++e) vv[e] = (OA[m * 4 + t][e] + pv[e]) * rlA;
          *(floatx4*)(opA + (m * 4 + t) * 16) = vv;
          pv = *(const floatx4*)&Lf[((hp * 2 + 1) * 4 + t) * 256 + lfb];
#pragma unroll
          for (int e = 0; e < 4; ++e) vv[e] = (OB[m * 4 + t][e] + pv[e]) * rlB;
          *(floatx4*)(opB + (m * 4 + t) * 16) = vv;
        }
      }
      __syncthreads();   // also frees smem for next tile's Q staging
    }
  }
}

extern "C" void kernel_launch(void* const* d_in, const int* in_sizes, int n_in,
                              void* d_out, int out_size, void* d_ws, size_t ws_size,
                              hipStream_t stream) {
  const float* q = (const float*)d_in[0];
  const float* k = (const float*)d_in[1];
  const float* v = (const float*)d_in[2];
  const int* positions = (const int*)d_in[3];
  const float* sinks = (const float*)d_in[4];
  float* out = (float*)d_out;

  ushort_t* Kr = (ushort_t*)d_ws;                   // 4 MB
  ushort_t* Vt = Kr + (size_t)NKV * S_LEN * HD;     // 4 MB (tiled layout)

  prep_kv<<<NKV * (S_LEN / 16), 256, 0, stream>>>(k, v, positions, Kr, Vt);
  attn_kernel<<<NKV * 96, 256, 0, stream>>>(q, positions, sinks, Kr, Vt, out);
}